// Round 9
// baseline (18504.028 us; speedup 1.0000x reference)
//
#include <hip/hip_runtime.h>
#include <math.h>

#define N_ITERS 200
#define B_DIM 128
#define K_DIM 10000
#define KP2 10240           /* Z cols / Dth cols (contraction dim) */
#define KB  10112           /* Dh rows / G2 col range: 316 x 32 */
#define D_DIM 1024
#define ALPHA_F 4.8828125e-6f   /* 0.01 / 2048 */

typedef unsigned short u16;
typedef __attribute__((ext_vector_type(8))) short bf16x8;
typedef __attribute__((ext_vector_type(4))) float f32x4;
#define MFMA __builtin_amdgcn_mfma_f32_16x16x32_bf16

__device__ __forceinline__ u16 f2bf(float x) {
    unsigned u = __float_as_uint(x);
    u += 0x7fff + ((u >> 16) & 1);
    return (u16)(u >> 16);
}
__device__ __forceinline__ float bf2f(u16 h) {
    return __uint_as_float(((unsigned)h) << 16);
}
__device__ __forceinline__ void split2(float x, u16& h, u16& l) {
    u16 hh = f2bf(x);
    h = hh;
    l = f2bf(x - bf2f(hh));
}
__device__ __forceinline__ int swz(int r) { return (r & 3) ^ ((r >> 2) & 1); }

__device__ __forceinline__ void gl2lds16(const u16* g, u16* l) {
    __builtin_amdgcn_global_load_lds(
        (const __attribute__((address_space(1))) unsigned int*)g,
        (__attribute__((address_space(3))) unsigned int*)l,
        16, 0, 0);
}

// ---------------------------------------------------------------------------
// init: out (W+score)=0, Zh/Zl=0, U0=-emb, G=0, u0=0, scal=0
// ---------------------------------------------------------------------------
__global__ __launch_bounds__(256) void k_init(float* __restrict__ out,
                                              u16* __restrict__ Zh, u16* __restrict__ Zl,
                                              const float* __restrict__ emb,
                                              float* __restrict__ U0,
                                              float* __restrict__ G,
                                              float* __restrict__ u0,
                                              float* __restrict__ scal) {
    int idx = blockIdx.x * 256 + threadIdx.x;
    int stride = gridDim.x * 256;
    for (int i = idx; i <= B_DIM * K_DIM; i += stride) out[i] = 0.0f;
    unsigned* zh = (unsigned*)Zh;
    unsigned* zl = (unsigned*)Zl;
    for (int i = idx; i < B_DIM * KP2 / 2; i += stride) { zh[i] = 0u; zl[i] = 0u; }
    for (int i = idx; i < B_DIM * D_DIM; i += stride) U0[i] = -emb[i];
    for (int i = idx; i < D_DIM * D_DIM; i += stride) G[i] = 0.0f;
    for (int i = idx; i < D_DIM; i += stride) u0[i] = 0.0f;
    for (int i = idx; i < 64; i += stride) scal[i] = 0.0f;
}

// ---------------------------------------------------------------------------
// D fp32 [10000,1024] -> Dh/Dl [KB,1024] and Dth/Dtl [1024,KP2] (pads zero)
// ---------------------------------------------------------------------------
__global__ __launch_bounds__(256) void k_convertD(const float* __restrict__ D,
                                                  u16* __restrict__ Dh,
                                                  u16* __restrict__ Dl,
                                                  u16* __restrict__ Dth,
                                                  u16* __restrict__ Dtl) {
    __shared__ u16 Th[32][33], Tl[32][33];
    int tx = threadIdx.x & 31, ty = threadIdx.x >> 5;
    int k0 = blockIdx.x * 32, d0 = blockIdx.y * 32;
    #pragma unroll
    for (int r = 0; r < 4; ++r) {
        int krow = k0 + ty + r * 8;
        float val = (krow < K_DIM) ? D[(size_t)krow * D_DIM + d0 + tx] : 0.0f;
        u16 h, l; split2(val, h, l);
        if (krow < KB) {
            Dh[(size_t)krow * D_DIM + d0 + tx] = h;
            Dl[(size_t)krow * D_DIM + d0 + tx] = l;
        }
        Th[ty + r * 8][tx] = h;
        Tl[ty + r * 8][tx] = l;
    }
    __syncthreads();
    #pragma unroll
    for (int r = 0; r < 4; ++r) {
        int d = d0 + ty + r * 8;
        int k = k0 + tx;
        Dth[(size_t)d * KP2 + k] = Th[tx][ty + r * 8];
        Dtl[(size_t)d * KP2 + k] = Tl[tx][ty + r * 8];
    }
}

// ---------------------------------------------------------------------------
// u0 = ones(10000) @ D  (column sums, fp32)
// ---------------------------------------------------------------------------
__global__ __launch_bounds__(256) void k_colsum(const float* __restrict__ D,
                                                float* __restrict__ u0) {
    int t = threadIdx.x;
    int kbase = blockIdx.x * 40;
    float a0 = 0.f, a1 = 0.f, a2 = 0.f, a3 = 0.f;
    for (int k = kbase; k < kbase + 40; ++k) {
        const float* row = D + (size_t)k * D_DIM;
        a0 += row[t];
        a1 += row[t + 256];
        a2 += row[t + 512];
        a3 += row[t + 768];
    }
    atomicAdd(&u0[t], a0);
    atomicAdd(&u0[t + 256], a1);
    atomicAdd(&u0[t + 512], a2);
    atomicAdd(&u0[t + 768], a3);
}

// ---------------------------------------------------------------------------
// k_mm (Gram only): G[128-tile][128-tile] += Dth-rows @ Dth-rows^T
// 256 thr / 4 waves of 64x64; atomic accumulate (4-way, one-time cost).
// ---------------------------------------------------------------------------
__global__ __launch_bounds__(256, 2) void k_mm(const u16* Ah_g, const u16* Al_g, long sA,
                                               const u16* Bh_g, const u16* Bl_g, long sB,
                                               int ksteps, float* __restrict__ out,
                                               int outStride) {
    __shared__ __align__(16) u16 lds[32768];
    int t = threadIdx.x;
    int arow0 = blockIdx.y * 128;
    int brow0 = blockIdx.x * 128;
    size_t k0 = (size_t)blockIdx.z * ksteps * 32;

    int w4 = t >> 6, lane = t & 63, quad = lane >> 4, lr = lane & 15;
    int wm = (w4 >> 1) * 64, wn = (w4 & 1) * 64;

    int rlo = w4 * 32 + (lane >> 2);
    int rhi = rlo + 16;
    int qs = lane & 3;
    const u16* sAh0 = Ah_g + (size_t)(arow0 + rlo) * sA + k0 + (qs ^ swz(rlo)) * 8;
    const u16* sAh1 = Ah_g + (size_t)(arow0 + rhi) * sA + k0 + (qs ^ swz(rhi)) * 8;
    const u16* sAl0 = Al_g + (size_t)(arow0 + rlo) * sA + k0 + (qs ^ swz(rlo)) * 8;
    const u16* sAl1 = Al_g + (size_t)(arow0 + rhi) * sA + k0 + (qs ^ swz(rhi)) * 8;
    const u16* sBh0 = Bh_g + (size_t)(brow0 + rlo) * sB + k0 + (qs ^ swz(rlo)) * 8;
    const u16* sBh1 = Bh_g + (size_t)(brow0 + rhi) * sB + k0 + (qs ^ swz(rhi)) * 8;
    const u16* sBl0 = Bl_g + (size_t)(brow0 + rlo) * sB + k0 + (qs ^ swz(rlo)) * 8;
    const u16* sBl1 = Bl_g + (size_t)(brow0 + rhi) * sB + k0 + (qs ^ swz(rhi)) * 8;
    int dbase = w4 * 1024 + lane * 8;

    int offAH[4], offAL[4], offBH[4], offBL[4];
    #pragma unroll
    for (int mi = 0; mi < 4; ++mi) {
        int rr = wm + mi * 16 + lr;
        int o = rr * 32 + ((quad ^ swz(rr)) * 8);
        offAH[mi] = o; offAL[mi] = 4096 + o;
    }
    #pragma unroll
    for (int ni = 0; ni < 4; ++ni) {
        int rr = wn + ni * 16 + lr;
        int o = rr * 32 + ((quad ^ swz(rr)) * 8);
        offBH[ni] = 8192 + o; offBL[ni] = 12288 + o;
    }

    f32x4 acc[4][4];
    #pragma unroll
    for (int mi = 0; mi < 4; ++mi)
        #pragma unroll
        for (int ni = 0; ni < 4; ++ni) acc[mi][ni] = (f32x4){0.f, 0.f, 0.f, 0.f};

    auto stage = [&](int s, int buf) {
        u16* b = lds + buf * 16384;
        size_t c = (size_t)s * 32;
        gl2lds16(sAh0 + c, b + dbase);
        gl2lds16(sAh1 + c, b + 512 + dbase);
        gl2lds16(sAl0 + c, b + 4096 + dbase);
        gl2lds16(sAl1 + c, b + 4608 + dbase);
        gl2lds16(sBh0 + c, b + 8192 + dbase);
        gl2lds16(sBh1 + c, b + 8704 + dbase);
        gl2lds16(sBl0 + c, b + 12288 + dbase);
        gl2lds16(sBl1 + c, b + 12800 + dbase);
    };

    stage(0, 0);
    for (int s = 0; s < ksteps; ++s) {
        __syncthreads();
        if (s + 1 < ksteps) stage(s + 1, (s + 1) & 1);
        u16* b = lds + (s & 1) * 16384;
        bf16x8 aH[4], aL[4], bH[4], bL[4];
        #pragma unroll
        for (int i = 0; i < 4; ++i) {
            aH[i] = *(const bf16x8*)&b[offAH[i]];
            aL[i] = *(const bf16x8*)&b[offAL[i]];
            bH[i] = *(const bf16x8*)&b[offBH[i]];
            bL[i] = *(const bf16x8*)&b[offBL[i]];
        }
        #pragma unroll
        for (int mi = 0; mi < 4; ++mi)
            #pragma unroll
            for (int ni = 0; ni < 4; ++ni) {
                acc[mi][ni] = MFMA(aL[mi], bH[ni], acc[mi][ni], 0, 0, 0);
                acc[mi][ni] = MFMA(aH[mi], bL[ni], acc[mi][ni], 0, 0, 0);
                acc[mi][ni] = MFMA(aH[mi], bH[ni], acc[mi][ni], 0, 0, 0);
            }
    }
    #pragma unroll
    for (int mi = 0; mi < 4; ++mi)
        #pragma unroll
        for (int ni = 0; ni < 4; ++ni) {
            int col = brow0 + wn + ni * 16 + lr;
            #pragma unroll
            for (int r = 0; r < 4; ++r) {
                int row = arow0 + wm + mi * 16 + quad * 4 + r;
                atomicAdd(&out[(size_t)row * outStride + col], acc[mi][ni][r]);
            }
        }
}

// ---------------------------------------------------------------------------
// power step in u-space on Gram G. grid 256 x 256.
// ---------------------------------------------------------------------------
__global__ __launch_bounds__(256) void k_pstep(const float* __restrict__ G,
                                               const float* __restrict__ u0,
                                               const float* __restrict__ wvin,
                                               float* __restrict__ wvout,
                                               float* __restrict__ scal, int pw) {
    int t = threadIdx.x;
    int c = blockIdx.x * 4 + (t >> 6);
    int lane = t & 63;
    float rsX = (pw > 0) ? rsqrtf(scal[1 + pw]) : 1.0f;
    float a = 0.f;
    const float* Gr = G + (size_t)c * D_DIM;
    #pragma unroll
    for (int j = 0; j < 16; ++j) {
        int r = lane + j * 64;
        float ur = (pw == 0) ? u0[r] : wvin[r] * rsX;
        a = fmaf(ur, Gr[r], a);
    }
    #pragma unroll
    for (int o = 32; o > 0; o >>= 1) a += __shfl_down(a, o, 64);
    if (lane == 0) {
        float uc = (pw == 0) ? u0[c] : wvin[c] * rsX;
        wvout[c] = a;
        atomicAdd(&scal[2 + pw], a * uc);
    }
}

__global__ void k_Lfin(float* __restrict__ scal) {
    float stepv = 1024.0f / sqrtf(scal[2 + 30]);
    scal[0] = stepv;
    scal[1] = stepv * ALPHA_F;
}

// ---------------------------------------------------------------------------
// k_g1: U[128, n0:+32] += Z[128, ks*1280:+1280] @ Dth-rows^T   (atomic fp32)
// grid (32 d-tiles, 8 ksplits) = 256 blocks, 128 thr (2 waves of 64m x 32n),
// 40 ksteps. LDS/stage (u16): Ah@0[128][32] Al@4096 Bh@8192[32][32] Bl@9216.
// U was pre-initialized to -emb (or 0 for recon), so result = Z@D - Y.
// ---------------------------------------------------------------------------
__global__ __launch_bounds__(128, 2) void k_g1(const u16* __restrict__ Zh,
                                               const u16* __restrict__ Zl,
                                               const u16* __restrict__ Dth,
                                               const u16* __restrict__ Dtl,
                                               float* __restrict__ U) {
    __shared__ __align__(16) u16 lds[20480];
    int t = threadIdx.x;
    int n0 = blockIdx.x * 32;
    size_t kbase = (size_t)blockIdx.y * 1280;
    int w = t >> 6, lane = t & 63, quad = lane >> 4, lr = lane & 15;
    int rl = lane >> 2, qs = lane & 3;

    int rA = w * 64 + rl;
    const u16* pAh[4];
    const u16* pAl[4];
    #pragma unroll
    for (int j = 0; j < 4; ++j) {
        int r = rA + j * 16;
        pAh[j] = Zh + (size_t)r * KP2 + kbase + (qs ^ swz(r)) * 8;
        pAl[j] = Zl + (size_t)r * KP2 + kbase + (qs ^ swz(r)) * 8;
    }
    int rB = w * 16 + rl;
    const u16* pBh = Dth + (size_t)(n0 + rB) * KP2 + kbase + (qs ^ swz(rB)) * 8;
    const u16* pBl = Dtl + (size_t)(n0 + rB) * KP2 + kbase + (qs ^ swz(rB)) * 8;
    int dA = w * 2048 + lane * 8;
    int dB = w * 512 + lane * 8;

    int offAH[4], offAL[4], offBH[2], offBL[2];
    #pragma unroll
    for (int mi = 0; mi < 4; ++mi) {
        int rr = w * 64 + mi * 16 + lr;
        int o = rr * 32 + ((quad ^ swz(rr)) * 8);
        offAH[mi] = o; offAL[mi] = 4096 + o;
    }
    #pragma unroll
    for (int ni = 0; ni < 2; ++ni) {
        int rr = ni * 16 + lr;
        int o = rr * 32 + ((quad ^ swz(rr)) * 8);
        offBH[ni] = 8192 + o; offBL[ni] = 9216 + o;
    }

    f32x4 acc[4][2];
    #pragma unroll
    for (int mi = 0; mi < 4; ++mi)
        #pragma unroll
        for (int ni = 0; ni < 2; ++ni) acc[mi][ni] = (f32x4){0.f, 0.f, 0.f, 0.f};

    auto stage = [&](int s, int buf) {
        u16* b = lds + buf * 10240;
        size_t c = (size_t)s * 32;
        #pragma unroll
        for (int j = 0; j < 4; ++j) {
            gl2lds16(pAh[j] + c, b + dA + j * 512);
            gl2lds16(pAl[j] + c, b + 4096 + dA + j * 512);
        }
        gl2lds16(pBh + c, b + 8192 + dB);
        gl2lds16(pBl + c, b + 9216 + dB);
    };

    stage(0, 0);
    for (int s = 0; s < 40; ++s) {
        __syncthreads();
        if (s + 1 < 40) stage(s + 1, (s + 1) & 1);
        u16* b = lds + (s & 1) * 10240;
        bf16x8 aH[4], aL[4], bH[2], bL[2];
        #pragma unroll
        for (int i = 0; i < 4; ++i) {
            aH[i] = *(const bf16x8*)&b[offAH[i]];
            aL[i] = *(const bf16x8*)&b[offAL[i]];
        }
        #pragma unroll
        for (int i = 0; i < 2; ++i) {
            bH[i] = *(const bf16x8*)&b[offBH[i]];
            bL[i] = *(const bf16x8*)&b[offBL[i]];
        }
        #pragma unroll
        for (int mi = 0; mi < 4; ++mi)
            #pragma unroll
            for (int ni = 0; ni < 2; ++ni) {
                acc[mi][ni] = MFMA(aL[mi], bH[ni], acc[mi][ni], 0, 0, 0);
                acc[mi][ni] = MFMA(aH[mi], bL[ni], acc[mi][ni], 0, 0, 0);
                acc[mi][ni] = MFMA(aH[mi], bH[ni], acc[mi][ni], 0, 0, 0);
            }
    }
    #pragma unroll
    for (int mi = 0; mi < 4; ++mi)
        #pragma unroll
        for (int ni = 0; ni < 2; ++ni) {
            int d = n0 + ni * 16 + lr;
            #pragma unroll
            for (int r = 0; r < 4; ++r) {
                int i = w * 64 + mi * 16 + quad * 4 + r;
                atomicAdd(&U[(size_t)i * D_DIM + d], acc[mi][ni][r]);
            }
        }
}

// ---------------------------------------------------------------------------
// k_g2: acc[128, n0:+32] = Ures_fp32[128,1024] @ Dh-rows^T ; fused FISTA prox.
// A staged fp32 -> split-bf16 in LDS (redundant per block; VALU overlaps MFMA).
// grid 316 x 128 thr (2 waves, wave-tile 64m x 32n), 32 ksteps.
// Epilogue: prox (W, Zh/Zl) and init Unext = -emb (or 0 when writeW).
// ---------------------------------------------------------------------------
__global__ __launch_bounds__(128, 2) void k_g2(const float* __restrict__ Ures,
                                               const u16* __restrict__ Dh,
                                               const u16* __restrict__ Dl,
                                               const float* __restrict__ emb,
                                               float* __restrict__ W,
                                               u16* __restrict__ Zh, u16* __restrict__ Zl,
                                               const float* __restrict__ scal,
                                               float mom, int writeW,
                                               float* __restrict__ Unext) {
    __shared__ __align__(16) u16 lds[20480];
    int t = threadIdx.x;
    int n0 = blockIdx.x * 32;
    int w = t >> 6, lane = t & 63, quad = lane >> 4, lr = lane & 15;
    int rl = lane >> 2, qs = lane & 3;

    // A staging: 4 row-groups; fp32 load + split + ds_write (swizzled slots)
    int arow[4];
    const float* pA[4];
    #pragma unroll
    for (int j = 0; j < 4; ++j) {
        arow[j] = w * 64 + rl + j * 16;
        pA[j] = Ures + (size_t)arow[j] * D_DIM + qs * 8;
    }
    // B staging: async bf16 pairs
    int rB = w * 16 + rl;
    const u16* pBh = Dh + (size_t)(n0 + rB) * D_DIM + (qs ^ swz(rB)) * 8;
    const u16* pBl = Dl + (size_t)(n0 + rB) * D_DIM + (qs ^ swz(rB)) * 8;
    int dB = w * 512 + lane * 8;

    int offAH[4], offAL[4], offBH[2], offBL[2];
    #pragma unroll
    for (int mi = 0; mi < 4; ++mi) {
        int rr = w * 64 + mi * 16 + lr;
        int o = rr * 32 + ((quad ^ swz(rr)) * 8);
        offAH[mi] = o; offAL[mi] = 4096 + o;
    }
    #pragma unroll
    for (int ni = 0; ni < 2; ++ni) {
        int rr = ni * 16 + lr;
        int o = rr * 32 + ((quad ^ swz(rr)) * 8);
        offBH[ni] = 8192 + o; offBL[ni] = 9216 + o;
    }

    f32x4 acc[4][2];
    #pragma unroll
    for (int mi = 0; mi < 4; ++mi)
        #pragma unroll
        for (int ni = 0; ni < 2; ++ni) acc[mi][ni] = (f32x4){0.f, 0.f, 0.f, 0.f};

    auto stage = [&](int s, int buf) {
        u16* b = lds + buf * 10240;
        size_t c = (size_t)s * 32;
        gl2lds16(pBh + c, b + 8192 + dB);
        gl2lds16(pBl + c, b + 9216 + dB);
        #pragma unroll
        for (int j = 0; j < 4; ++j) {
            float v[8];
            *(float4*)&v[0] = *(const float4*)(pA[j] + c);
            *(float4*)&v[4] = *(const float4*)(pA[j] + c + 4);
            union { u16 us[8]; int4 q; } hu, lu;
            #pragma unroll
            for (int e = 0; e < 8; ++e) split2(v[e], hu.us[e], lu.us[e]);
            int dst = arow[j] * 32 + ((qs ^ swz(arow[j])) * 8);
            *(int4*)&b[dst] = hu.q;
            *(int4*)&b[4096 + dst] = lu.q;
        }
    };

    stage(0, 0);
    for (int s = 0; s < 32; ++s) {
        __syncthreads();
        if (s + 1 < 32) stage(s + 1, (s + 1) & 1);
        u16* b = lds + (s & 1) * 10240;
        bf16x8 aH[4], aL[4], bH[2], bL[2];
        #pragma unroll
        for (int i = 0; i < 4; ++i) {
            aH[i] = *(const bf16x8*)&b[offAH[i]];
            aL[i] = *(const bf16x8*)&b[offAL[i]];
        }
        #pragma unroll
        for (int i = 0; i < 2; ++i) {
            bH[i] = *(const bf16x8*)&b[offBH[i]];
            bL[i] = *(const bf16x8*)&b[offBL[i]];
        }
        #pragma unroll
        for (int mi = 0; mi < 4; ++mi)
            #pragma unroll
            for (int ni = 0; ni < 2; ++ni) {
                acc[mi][ni] = MFMA(aL[mi], bH[ni], acc[mi][ni], 0, 0, 0);
                acc[mi][ni] = MFMA(aH[mi], bL[ni], acc[mi][ni], 0, 0, 0);
                acc[mi][ni] = MFMA(aH[mi], bH[ni], acc[mi][ni], 0, 0, 0);
            }
    }

    const float invN = 1.0f / 1024.0f;
    float stepv = scal[0], th = scal[1];
    #pragma unroll
    for (int mi = 0; mi < 4; ++mi)
        #pragma unroll
        for (int ni = 0; ni < 2; ++ni) {
            int k = n0 + ni * 16 + lr;
            #pragma unroll
            for (int r = 0; r < 4; ++r) {
                int i = w * 64 + mi * 16 + quad * 4 + r;
                size_t iz = (size_t)i * KP2 + k;
                float g = acc[mi][ni][r] * invN;
                float z = bf2f(Zh[iz]) + bf2f(Zl[iz]);
                float wold = (k < K_DIM) ? W[(size_t)i * K_DIM + k] : 0.0f;
                float wnew = fmaxf(z - stepv * g - th, 0.0f);
                float zn = wnew + mom * (wnew - wold);
                if (k < K_DIM) W[(size_t)i * K_DIM + k] = wnew;
                u16 h, l;
                split2(writeW ? wnew : zn, h, l);
                Zh[iz] = h; Zl[iz] = l;
            }
        }
    // init next iteration's U accumulator: -emb (FISTA) or 0 (recon pass)
    for (int i = blockIdx.x * 128 + t; i < B_DIM * D_DIM; i += gridDim.x * 128)
        Unext[i] = writeW ? 0.0f : -emb[i];
}

// ---------------------------------------------------------------------------
// score = sum_i <recon_i, emb_i> / (||recon_i|| + 1e-12); recon fp32 in U
// ---------------------------------------------------------------------------
__global__ __launch_bounds__(256) void k_score(const float* __restrict__ U,
                                               const float* __restrict__ emb,
                                               float* __restrict__ score) {
    int wid = blockIdx.x * 4 + (threadIdx.x >> 6);
    int lane = threadIdx.x & 63;
    if (wid >= B_DIM) return;
    float rr = 0.f, re = 0.f;
    #pragma unroll
    for (int j = 0; j < D_DIM; j += 64) {
        int idx = wid * D_DIM + j + lane;
        float x = U[idx];
        rr = fmaf(x, x, rr);
        re = fmaf(x, emb[idx], re);
    }
    #pragma unroll
    for (int off = 32; off > 0; off >>= 1) {
        rr += __shfl_down(rr, off, 64);
        re += __shfl_down(re, off, 64);
    }
    if (lane == 0) atomicAdd(score, re / (sqrtf(rr) + 1e-12f));
}

// ---------------------------------------------------------------------------
extern "C" void kernel_launch(void* const* d_in, const int* in_sizes, int n_in,
                              void* d_out, int out_size, void* d_ws, size_t ws_size,
                              hipStream_t stream) {
    const float* emb = (const float*)d_in[0];   // [128,1024]
    const float* Dm  = (const float*)d_in[1];   // [10000,1024]
    float* out = (float*)d_out;
    float* W = out;                             // [128][10000] in d_out

    size_t off = 0;
    auto carve = [&](size_t bytes) -> void* {
        void* r = (char*)d_ws + off;
        off += (bytes + 255) & ~(size_t)255;
        return r;
    };
    float* G    = (float*)carve((size_t)D_DIM * D_DIM * 4);      // 4.19 MB
    float* U0   = (float*)carve((size_t)B_DIM * D_DIM * 4);      // 0.52 MB
    float* U1   = (float*)carve((size_t)B_DIM * D_DIM * 4);
    u16*   Zh   = (u16*)carve((size_t)B_DIM * KP2 * 2);          // 2.62 MB
    u16*   Zl   = (u16*)carve((size_t)B_DIM * KP2 * 2);
    float* u0   = (float*)carve(D_DIM * 4);
    float* wva  = (float*)carve(D_DIM * 4);
    float* wvb  = (float*)carve(D_DIM * 4);
    float* scal = (float*)carve(64 * 4);
    u16*   Dh   = (u16*)carve((size_t)KB * D_DIM * 2);           // 20.7 MB
    u16*   Dl   = (u16*)carve((size_t)KB * D_DIM * 2);
    u16*   Dth  = (u16*)carve((size_t)D_DIM * KP2 * 2);          // 21.0 MB
    u16*   Dtl  = (u16*)carve((size_t)D_DIM * KP2 * 2);

    k_init<<<512, 256, 0, stream>>>(out, Zh, Zl, emb, U0, G, u0, scal);
    k_convertD<<<dim3(320, 32), 256, 0, stream>>>(Dm, Dh, Dl, Dth, Dtl);
    k_colsum<<<250, 256, 0, stream>>>(Dm, u0);

    // Gram G = Dth @ Dth^T (1024x1024 over K=10240), split-K=4, atomic accum
    k_mm<<<dim3(8, 8, 4), 256, 0, stream>>>(Dth, Dtl, (long)KP2,
                                            Dth, Dtl, (long)KP2,
                                            80, G, D_DIM);

    // power iteration in u-space
    for (int pw = 0; pw <= 30; ++pw) {
        float* win  = (pw & 1) ? wva : wvb;
        float* wout = (pw & 1) ? wvb : wva;
        k_pstep<<<256, 256, 0, stream>>>(G, u0, win, wout, scal, pw);
    }
    k_Lfin<<<1, 1, 0, stream>>>(scal);

    // ---- FISTA: 2 launches per iteration ----
    double t = 1.0;
    for (int it = 0; it < N_ITERS; ++it) {
        double tn = 0.5 * (1.0 + sqrt(1.0 + 4.0 * t * t));
        float mom = (float)((t - 1.0) / tn);
        t = tn;
        float* Ucur  = (it & 1) ? U1 : U0;
        float* Unext = (it & 1) ? U0 : U1;
        k_g1<<<dim3(32, 8), 128, 0, stream>>>(Zh, Zl, Dth, Dtl, Ucur);
        k_g2<<<316, 128, 0, stream>>>(Ucur, Dh, Dl, emb, W, Zh, Zl, scal, mom,
                                      (it == N_ITERS - 1) ? 1 : 0, Unext);
    }

    // recon = W@D into U0 (zeroed by last k_g2; Zh/Zl hold split W), score
    k_g1<<<dim3(32, 8), 128, 0, stream>>>(Zh, Zl, Dth, Dtl, U0);
    k_score<<<32, 256, 0, stream>>>(U0, emb, out + (size_t)B_DIM * K_DIM);
}